// Round 8
// baseline (1931.076 us; speedup 1.0000x reference)
//
#include <hip/hip_runtime.h>
#include <hip/hip_bf16.h>
#include <stdint.h>
#include <math.h>

// POD_GalerkinTransformer forward, MI355X (gfx950).
// fp16 MFMA pipeline (R7-proven numerics: absmax 1024 vs 6594 threshold).
// R8: qkv -> 256x256 8-wave BK64 phase-split kernel (swizzled LDS, counted
// waits, setprio); W1 -> gated 128x256 BK32 variant + fast tanh-GELU.
// Wout/W2/embed/final stay on the 128x128 kernel. Attention unchanged.

typedef _Float16 f16x8 __attribute__((ext_vector_type(8)));
typedef float f32x4 __attribute__((ext_vector_type(4)));
typedef unsigned short u16x8 __attribute__((ext_vector_type(8)));
typedef unsigned short u16;

#define SEQ 4096
#define NTOK 16384
#define HID 512
#define RSCL 256.0f
#define RSCLI (1.0f/256.0f)

__device__ __forceinline__ float wred(float x) {
#pragma unroll
  for (int off = 32; off; off >>= 1) x += __shfl_xor(x, off);
  return x;
}

__device__ __forceinline__ u16 f2h(float v) {
  _Float16 h = (_Float16)v;
  return __builtin_bit_cast(u16, h);
}
__device__ __forceinline__ float h2f(u16 u) {
  return (float)__builtin_bit_cast(_Float16, u);
}

__device__ __forceinline__ float fgelu(float a) {
  // tanh-form GELU; |err| <= ~3e-4 of unit scale, saturates correctly at +-inf
  float t = 0.7978845608f * a * (1.0f + 0.044715f * a * a);
  float e = __expf(2.0f * t);
  float th = 1.0f - 2.0f / (e + 1.0f);
  return 0.5f * a * (1.0f + th);
}

__device__ __forceinline__ void gload16(const void* g, void* l) {
  __builtin_amdgcn_global_load_lds(
      reinterpret_cast<const __attribute__((address_space(1))) int*>(
          reinterpret_cast<uintptr_t>(g)),
      reinterpret_cast<__attribute__((address_space(3))) int*>(
          reinterpret_cast<uintptr_t>(l)),
      16, 0, 0);
}

// ------- weight transpose+cast: [D][K][N] f32 -> [D][N][K] fp16 ------------
__global__ __launch_bounds__(256) void k_transpose(const float* __restrict__ src,
                                                   u16* __restrict__ dst,
                                                   int K, int N) {
  int d = blockIdx.z;
  const float* s = src + (size_t)d * K * N;
  u16* o = dst + (size_t)d * N * K;
  int k0 = blockIdx.x * 64, n0 = blockIdx.y * 64;
  __shared__ float tile[64][65];
  int t = threadIdx.x, c = t & 63, r4 = t >> 6;
#pragma unroll
  for (int i = 0; i < 16; ++i) {
    int r = i * 4 + r4;
    tile[r][c] = s[(size_t)(k0 + r) * N + n0 + c];
  }
  __syncthreads();
#pragma unroll
  for (int i = 0; i < 16; ++i) {
    int r = i * 4 + r4;
    o[(size_t)(n0 + r) * K + k0 + c] = f2h(tile[c][r]);
  }
}

// ------- pack x: [4][64][4096][2] f32 -> XP[16384][128] fp16 ---------------
__global__ __launch_bounds__(256) void k_packx(const float* __restrict__ x,
                                               u16* __restrict__ XP) {
  int idx = blockIdx.x * 256 + threadIdx.x;
  int k = idx & 127, row = idx >> 7;
  int b = row >> 12, n = row & 4095;
  int tt = k >> 1, c = k & 1;
  XP[idx] = f2h(x[(((size_t)(b * 64 + tt)) * SEQ + n) * 2 + c]);
}

// ------- LayerNorm: H f32 [NTOK][512] -> Y fp16 ----------------------------
__global__ __launch_bounds__(256) void k_ln(const float* __restrict__ H,
                                            const float* __restrict__ G,
                                            const float* __restrict__ B,
                                            u16* __restrict__ Y) {
  int t = threadIdx.x, lane = t & 63;
  int row = blockIdx.x * 4 + (t >> 6);
  const float4* h4 = (const float4*)(H + (size_t)row * HID);
  float4 a = h4[lane * 2], b = h4[lane * 2 + 1];
  float v[8] = {a.x, a.y, a.z, a.w, b.x, b.y, b.z, b.w};
  float s = v[0] + v[1] + v[2] + v[3] + v[4] + v[5] + v[6] + v[7];
  s = wred(s);
  float m = s * (1.0f / 512.0f);
  float q = 0.f;
#pragma unroll
  for (int i = 0; i < 8; ++i) {
    v[i] -= m;
    q += v[i] * v[i];
  }
  q = wred(q);
  float rs = rsqrtf(q * (1.0f / 512.0f) + 1e-5f);
  const float4* g4 = (const float4*)G;
  const float4* b4 = (const float4*)B;
  float4 g1 = g4[lane * 2], g2 = g4[lane * 2 + 1];
  float4 e1 = b4[lane * 2], e2 = b4[lane * 2 + 1];
  float gg[8] = {g1.x, g1.y, g1.z, g1.w, g2.x, g2.y, g2.z, g2.w};
  float ee[8] = {e1.x, e1.y, e1.z, e1.w, e2.x, e2.y, e2.z, e2.w};
  union { u16x8 v; u16 s_[8]; } uh;
#pragma unroll
  for (int i = 0; i < 8; ++i) uh.s_[i] = f2h(v[i] * rs * gg[i] + ee[i]);
  *reinterpret_cast<u16x8*>((u16*)Y + (size_t)row * HID + lane * 8) = uh.v;
}

// ------- dots partials -----------------------------------------------------
__global__ __launch_bounds__(256) void k_dots(const u16* __restrict__ QKV,
                                              float* __restrict__ DOTSP) {
  int bh = blockIdx.y, b = bh >> 3, h = bh & 7;
  int n0 = blockIdx.x * 512;
  __shared__ alignas(16) short ks[64 * 64];
  __shared__ alignas(16) short vs[64 * 64];
  int t = threadIdx.x;
  int d0 = (t & 15) * 4, e0 = (t >> 4) * 4;
  float acc[4][4] = {};
  for (int sub = 0; sub < 8; ++sub) {
    int nb = n0 + sub * 64;
#pragma unroll
    for (int i = 0; i < 2; ++i) {
      int c = t + i * 256;
      int r = c >> 3, off = (c & 7) << 3;
      const u16* base = QKV + (size_t)(b * SEQ + nb + r) * 1536;
      gload16(base + 512 + h * 64 + off, ks + c * 8);
      gload16(base + 1024 + h * 64 + off, vs + c * 8);
    }
    asm volatile("s_waitcnt vmcnt(0)" ::: "memory");
    __syncthreads();
    for (int r = 0; r < 64; ++r) {
      short4 kk = *(const short4*)&ks[r * 64 + d0];
      short4 vv = *(const short4*)&vs[r * 64 + e0];
      float kf[4] = {h2f((u16)kk.x), h2f((u16)kk.y), h2f((u16)kk.z), h2f((u16)kk.w)};
      float vf[4] = {h2f((u16)vv.x), h2f((u16)vv.y), h2f((u16)vv.z), h2f((u16)vv.w)};
#pragma unroll
      for (int i = 0; i < 4; ++i)
#pragma unroll
        for (int j = 0; j < 4; ++j) acc[i][j] += kf[i] * vf[j];
    }
    __syncthreads();
  }
  float* dst = DOTSP + ((size_t)blockIdx.x * 32 + bh) * 4096;
#pragma unroll
  for (int i = 0; i < 4; ++i)
#pragma unroll
    for (int j = 0; j < 4; ++j) dst[(d0 + i) * 64 + e0 + j] = acc[i][j];
}

__global__ __launch_bounds__(256) void k_reddots(const float* __restrict__ P,
                                                 float* __restrict__ D) {
  int i = blockIdx.x * 256 + threadIdx.x;
  float s = 0.f;
#pragma unroll
  for (int c = 0; c < 8; ++c) s += P[(size_t)c * 131072 + i];
  D[i] = s;
}

// ------- o = q @ dots * (1/n) ----------------------------------------------
__global__ __launch_bounds__(256) void k_ov(const u16* __restrict__ QKV,
                                            const float* __restrict__ DOTS,
                                            u16* __restrict__ O) {
  int bh = blockIdx.y, b = bh >> 3, h = bh & 7;
  int n0 = blockIdx.x * 64;
  __shared__ alignas(16) float ds[64 * 64];
  __shared__ alignas(16) short qs[64 * 64];
  int t = threadIdx.x;
  const float* dsrc = DOTS + (size_t)bh * 4096;
#pragma unroll
  for (int i = 0; i < 16; ++i) ds[t + i * 256] = dsrc[t + i * 256];
#pragma unroll
  for (int i = 0; i < 2; ++i) {
    int c = t + i * 256, r = c >> 3, off = (c & 7) << 3;
    gload16(QKV + (size_t)(b * SEQ + n0 + r) * 1536 + h * 64 + off, qs + c * 8);
  }
  asm volatile("s_waitcnt vmcnt(0)" ::: "memory");
  __syncthreads();
  int wv = t >> 6, lane = t & 63;
  for (int tok = wv; tok < 64; tok += 4) {
    float acc = 0.f;
#pragma unroll
    for (int d = 0; d < 64; d += 4) {
      short4 q4 = *(const short4*)&qs[tok * 64 + d];
      acc += h2f((u16)q4.x) * ds[(d + 0) * 64 + lane];
      acc += h2f((u16)q4.y) * ds[(d + 1) * 64 + lane];
      acc += h2f((u16)q4.z) * ds[(d + 2) * 64 + lane];
      acc += h2f((u16)q4.w) * ds[(d + 3) * 64 + lane];
    }
    O[(size_t)(b * SEQ + n0 + tok) * 512 + h * 64 + lane] = f2h(acc * (1.0f / SEQ));
  }
}

// ======== NEW 256x256 plain kernel (qkv, fused InstanceNorm epilogue) ======
// 512 thr / 8 waves (2M x 4N), wave tile 128x64, BK=64, dbuf 128KiB LDS,
// XOR-swizzled slots (2-way = free), 2 phases/K-tile, counted waits, setprio.
__device__ __forceinline__ void stP(const u16* g, int ldk, int rowBase, int k0,
                                    short* lds, int t, int i) {
  int c = t + i * 512;                       // 0..2047 -> 32KB tile
  int r = c >> 3, s = (c & 7) ^ (r & 7);     // pre-swizzled source slot
  gload16(g + (size_t)(rowBase + r) * ldk + k0 + s * 8, lds + c * 8);
}

__global__ __launch_bounds__(512, 2) void k_gemmP(
    const u16* __restrict__ A, int lda, const u16* __restrict__ BT, int K,
    u16* __restrict__ o16, int ldo) {
  __shared__ alignas(16) short sm[2][2][16384];   // 128 KiB
  const int t = threadIdx.x, lane = t & 63;
  const int w = t >> 6, wr = w >> 2, wcn = w & 3;
  const int r16 = lane & 15, grp = lane >> 4;
  const int mBase = blockIdx.y * 256, nBase = blockIdx.x * 256;
  const int NT = K >> 6;

  f32x4 acc[8][4] = {};

#pragma unroll
  for (int i = 0; i < 4; ++i) stP(A, lda, mBase, 0, &sm[0][0][0], t, i);
#pragma unroll
  for (int i = 0; i < 4; ++i) stP(BT, K, nBase, 0, &sm[0][1][0], t, i);
  __syncthreads();

  int buf = 0;
  for (int kt = 0; kt < NT; ++kt) {
    int k0n = (kt + 1) << 6;
    // ---- phase A (kk=0): stage next-A, read frags, MFMA
    if (kt + 1 < NT) {
#pragma unroll
      for (int i = 0; i < 4; ++i) stP(A, lda, mBase, k0n, &sm[buf ^ 1][0][0], t, i);
    }
    {
      f16x8 af[8], bf[4];
#pragma unroll
      for (int i = 0; i < 8; ++i) {
        int row = wr * 128 + i * 16 + r16;
        af[i] = *(const f16x8*)&sm[buf][0][row * 64 + ((grp) ^ (row & 7)) * 8];
      }
#pragma unroll
      for (int j = 0; j < 4; ++j) {
        int row = wcn * 64 + j * 16 + r16;
        bf[j] = *(const f16x8*)&sm[buf][1][row * 64 + ((grp) ^ (row & 7)) * 8];
      }
      __builtin_amdgcn_s_barrier();
      asm volatile("s_waitcnt lgkmcnt(0)" ::: "memory");
      __builtin_amdgcn_sched_barrier(0);
      __builtin_amdgcn_s_setprio(1);
#pragma unroll
      for (int i = 0; i < 8; ++i)
#pragma unroll
        for (int j = 0; j < 4; ++j)
          acc[i][j] = __builtin_amdgcn_mfma_f32_16x16x32_f16(af[i], bf[j], acc[i][j], 0, 0, 0);
      __builtin_amdgcn_s_setprio(0);
    }
    // ---- phase B (kk=1): stage next-B, read frags, MFMA
    if (kt + 1 < NT) {
#pragma unroll
      for (int i = 0; i < 4; ++i) stP(BT, K, nBase, k0n, &sm[buf ^ 1][1][0], t, i);
    }
    {
      f16x8 af[8], bf[4];
#pragma unroll
      for (int i = 0; i < 8; ++i) {
        int row = wr * 128 + i * 16 + r16;
        af[i] = *(const f16x8*)&sm[buf][0][row * 64 + ((4 + grp) ^ (row & 7)) * 8];
      }
#pragma unroll
      for (int j = 0; j < 4; ++j) {
        int row = wcn * 64 + j * 16 + r16;
        bf[j] = *(const f16x8*)&sm[buf][1][row * 64 + ((4 + grp) ^ (row & 7)) * 8];
      }
      __builtin_amdgcn_s_barrier();
      asm volatile("s_waitcnt lgkmcnt(0)" ::: "memory");
      __builtin_amdgcn_sched_barrier(0);
      __builtin_amdgcn_s_setprio(1);
#pragma unroll
      for (int i = 0; i < 8; ++i)
#pragma unroll
        for (int j = 0; j < 4; ++j)
          acc[i][j] = __builtin_amdgcn_mfma_f32_16x16x32_f16(af[i], bf[j], acc[i][j], 0, 0, 0);
      __builtin_amdgcn_s_setprio(0);
    }
    asm volatile("s_waitcnt vmcnt(0)" ::: "memory");
    __builtin_amdgcn_s_barrier();
    buf ^= 1;
  }

  // epilogue: fused InstanceNorm over each 64-col head group (k/v cols only)
  const bool doNorm = (nBase + wcn * 64) >= 512;
#pragma unroll
  for (int i = 0; i < 8; ++i) {
#pragma unroll
    for (int r = 0; r < 4; ++r) {
      float s = 0.f, s2 = 0.f;
#pragma unroll
      for (int j = 0; j < 4; ++j) {
        float v = acc[i][j][r];
        s += v;
        s2 += v * v;
      }
#pragma unroll
      for (int off = 8; off; off >>= 1) {
        s += __shfl_xor(s, off);
        s2 += __shfl_xor(s2, off);
      }
      float m = s * (1.0f / 64.0f);
      float var = fmaxf(s2 * (1.0f / 64.0f) - m * m, 0.f);
      float rs = rsqrtf(var + 1e-5f);
      int row = mBase + wr * 128 + i * 16 + grp * 4 + r;
#pragma unroll
      for (int j = 0; j < 4; ++j) {
        int col = nBase + wcn * 64 + j * 16 + r16;
        float v = acc[i][j][r];
        if (doNorm) v = (v - m) * rs;
        o16[(size_t)row * ldo + col] = f2h(v);
      }
    }
  }
}

// ======== NEW gated 128x256 kernel (W1): BK=32, 3 streams, 80KiB LDS =======
// paired-row swizzle (2 rows x 64B -> 8 slots) => conflict-free ds_read_b128.
__device__ __forceinline__ void stG(const u16* g, int ldk, int rowBase, int k0,
                                    short* lds, int t, int i) {
  int c = t + i * 512;
  int pr = c >> 3, s8 = (c & 7) ^ (pr & 7);
  int r = pr * 2 + (s8 >> 2);
  gload16(g + (size_t)(rowBase + r) * ldk + k0 + (s8 & 3) * 8, lds + c * 8);
}

#define IDXG(row) (((row) >> 1) * 64 + (((((row) & 1) << 2) | grp) ^ (((row) >> 1) & 7)) * 8)

__global__ __launch_bounds__(512, 2) void k_gemmG(
    const u16* __restrict__ A, int lda,
    const u16* __restrict__ B1, const u16* __restrict__ B2, int K,
    const float* __restrict__ bias, u16* __restrict__ o16, int ldo) {
  __shared__ alignas(16) short sm[2][20480];  // A 8KB | B1 16KB | B2 16KB per buf
  const int t = threadIdx.x, lane = t & 63;
  const int w = t >> 6, wr = w >> 2, wcn = w & 3;
  const int r16 = lane & 15, grp = lane >> 4;
  const int mBase = blockIdx.y * 128, nBase = blockIdx.x * 256;
  const int NT = K >> 5;

  f32x4 acc[4][4] = {};
  f32x4 acc2[4][4] = {};

  stG(A, lda, mBase, 0, &sm[0][0], t, 0);
#pragma unroll
  for (int i = 0; i < 2; ++i) stG(B1, K, nBase, 0, &sm[0][4096], t, i);
#pragma unroll
  for (int i = 0; i < 2; ++i) stG(B2, K, nBase, 0, &sm[0][12288], t, i);
  __syncthreads();

  int buf = 0;
  for (int kt = 0; kt < NT; ++kt) {
    int k0n = (kt + 1) << 5;
    f16x8 af[4], bv[4];
    // ---- phase A: stage next A+B1, read af+b1, MFMA acc
    if (kt + 1 < NT) {
      stG(A, lda, mBase, k0n, &sm[buf ^ 1][0], t, 0);
#pragma unroll
      for (int i = 0; i < 2; ++i) stG(B1, K, nBase, k0n, &sm[buf ^ 1][4096], t, i);
    }
#pragma unroll
    for (int i = 0; i < 4; ++i)
      af[i] = *(const f16x8*)&sm[buf][IDXG(wr * 64 + i * 16 + r16)];
#pragma unroll
    for (int j = 0; j < 4; ++j)
      bv[j] = *(const f16x8*)&sm[buf][4096 + IDXG(wcn * 64 + j * 16 + r16)];
    __builtin_amdgcn_s_barrier();
    asm volatile("s_waitcnt lgkmcnt(0)" ::: "memory");
    __builtin_amdgcn_sched_barrier(0);
    __builtin_amdgcn_s_setprio(1);
#pragma unroll
    for (int i = 0; i < 4; ++i)
#pragma unroll
      for (int j = 0; j < 4; ++j)
        acc[i][j] = __builtin_amdgcn_mfma_f32_16x16x32_f16(af[i], bv[j], acc[i][j], 0, 0, 0);
    __builtin_amdgcn_s_setprio(0);
    // ---- phase B: stage next B2, read b2, MFMA acc2 (af retained)
    if (kt + 1 < NT) {
#pragma unroll
      for (int i = 0; i < 2; ++i) stG(B2, K, nBase, k0n, &sm[buf ^ 1][12288], t, i);
    }
#pragma unroll
    for (int j = 0; j < 4; ++j)
      bv[j] = *(const f16x8*)&sm[buf][12288 + IDXG(wcn * 64 + j * 16 + r16)];
    __builtin_amdgcn_s_barrier();
    asm volatile("s_waitcnt lgkmcnt(0)" ::: "memory");
    __builtin_amdgcn_sched_barrier(0);
    __builtin_amdgcn_s_setprio(1);
#pragma unroll
    for (int i = 0; i < 4; ++i)
#pragma unroll
      for (int j = 0; j < 4; ++j)
        acc2[i][j] = __builtin_amdgcn_mfma_f32_16x16x32_f16(af[i], bv[j], acc2[i][j], 0, 0, 0);
    __builtin_amdgcn_s_setprio(0);
    asm volatile("s_waitcnt vmcnt(0)" ::: "memory");
    __builtin_amdgcn_s_barrier();
    buf ^= 1;
  }

  // epilogue: f = gelu(256*acc + b1) * (256*acc2 + b1g); store f/256 as fp16
#pragma unroll
  for (int i = 0; i < 4; ++i) {
#pragma unroll
    for (int j = 0; j < 4; ++j) {
#pragma unroll
      for (int r = 0; r < 4; ++r) {
        int row = mBase + wr * 64 + i * 16 + grp * 4 + r;
        int col = nBase + wcn * 64 + j * 16 + r16;
        float a = acc[i][j][r] * RSCL + bias[col];
        float c2 = acc2[i][j][r] * RSCL + bias[2048 + col];
        o16[(size_t)row * ldo + col] = f2h(fgelu(a) * c2 * RSCLI);
      }
    }
  }
}

// ------- 128x128 fp16 GEMM (embed / Wout / W2 / final) ---------------------
// MODE 0: H = (acc + bias)*sqrt(512) + posenc
// MODE 2: H = acc*ascale + bias + Hin; o16 = fp16(H/256)
// MODE 7: out32[b, col*4096+n] = 256*acc + bias
__device__ __forceinline__ void stage_t(const u16* g, int ldk, int rowBase,
                                        int k0, short* lds, int t) {
#pragma unroll
  for (int i = 0; i < 2; ++i) {
    int c = t + i * 256;
    int r = c >> 2, ko = (c & 3) << 3;
    gload16(g + (size_t)(rowBase + r) * ldk + k0 + ko, lds + c * 8);
  }
}

template <int MODE>
__global__ __launch_bounds__(256, 2) void k_gemm(
    const u16* __restrict__ A, const u16* __restrict__ B1, int K,
    const float* __restrict__ bias, const float* __restrict__ Hin,
    float ascale, float* __restrict__ out32, u16* __restrict__ o16, int ldo) {
  __shared__ alignas(16) short sm[2][2][128 * 32];
  const int t = threadIdx.x, lane = t & 63;
  const int wv = t >> 6, wr = wv >> 1, wc = wv & 1;
  const int r16 = lane & 15, grp = lane >> 4;
  const int mBase = blockIdx.y * 128, nBase = blockIdx.x * 128;
  const int NT = K >> 5;

  f32x4 acc[4][4] = {};

  stage_t(A, K, mBase, 0, &sm[0][0][0], t);
  stage_t(B1, K, nBase, 0, &sm[0][1][0], t);
  asm volatile("s_waitcnt vmcnt(0)" ::: "memory");
  __syncthreads();

  int buf = 0;
  for (int kt = 0; kt < NT; ++kt) {
    if (kt + 1 < NT) {
      stage_t(A, K, mBase, (kt + 1) << 5, &sm[buf ^ 1][0][0], t);
      stage_t(B1, K, nBase, (kt + 1) << 5, &sm[buf ^ 1][1][0], t);
    }
    const int fo = grp * 8;
    f16x8 af[4], b1v[4];
#pragma unroll
    for (int f = 0; f < 4; ++f)
      af[f] = *(const f16x8*)&sm[buf][0][(wr * 64 + f * 16 + r16) * 32 + fo];
#pragma unroll
    for (int f = 0; f < 4; ++f)
      b1v[f] = *(const f16x8*)&sm[buf][1][(wc * 64 + f * 16 + r16) * 32 + fo];
#pragma unroll
    for (int i = 0; i < 4; ++i)
#pragma unroll
      for (int j = 0; j < 4; ++j)
        acc[i][j] = __builtin_amdgcn_mfma_f32_16x16x32_f16(af[i], b1v[j], acc[i][j], 0, 0, 0);
    if (kt + 1 < NT) {
      asm volatile("s_waitcnt vmcnt(0)" ::: "memory");
      __syncthreads();
      buf ^= 1;
    }
  }

#pragma unroll
  for (int i = 0; i < 4; ++i) {
#pragma unroll
    for (int j = 0; j < 4; ++j) {
#pragma unroll
      for (int r = 0; r < 4; ++r) {
        int row = mBase + wr * 64 + i * 16 + grp * 4 + r;
        int col = nBase + wc * 64 + j * 16 + r16;
        float v = acc[i][j][r];
        if constexpr (MODE == 0) {
          v = (v + bias[col]) * 22.627416997969522f;
          int n = row & (SEQ - 1);
          int k2 = col >> 1;
          float ang = (float)n * expf((float)k2 * -0.03597789207803197f);
          v += (col & 1) ? cosf(ang) : sinf(ang);
          out32[(size_t)row * HID + col] = v;
        } else if constexpr (MODE == 2) {
          v = v * ascale + bias[col] + Hin[(size_t)row * HID + col];
          out32[(size_t)row * HID + col] = v;
          o16[(size_t)row * HID + col] = f2h(v * RSCLI);
        } else {  // MODE 7
          v = v * RSCL + bias[col];
          out32[(size_t)(row >> 12) * (128 * 4096) + (size_t)col * SEQ + (row & 4095)] = v;
        }
      }
    }
  }
}

// ---------------------------------------------------------------------------
extern "C" void kernel_launch(void* const* d_in, const int* in_sizes, int n_in,
                              void* d_out, int out_size, void* d_ws, size_t ws_size,
                              hipStream_t stream) {
  const float* x    = (const float*)d_in[0];
  const float* Wemb = (const float*)d_in[1];
  const float* bemb = (const float*)d_in[2];
  const float* lng  = (const float*)d_in[3];
  const float* lnb  = (const float*)d_in[4];
  const float* Wqkv = (const float*)d_in[5];
  const float* Wout = (const float*)d_in[6];
  const float* bout = (const float*)d_in[7];
  const float* W1   = (const float*)d_in[8];
  const float* b1   = (const float*)d_in[9];
  const float* W2   = (const float*)d_in[10];
  const float* b2   = (const float*)d_in[11];
  const float* Wd   = (const float*)d_in[12];
  const float* bd   = (const float*)d_in[13];

  char* p = (char*)d_ws;
  auto alloc = [&](size_t bytes) {
    char* r = p;
    p += (bytes + 255) & ~(size_t)255;
    return r;
  };
  // ---- total ~177MB (limit ~256MiB) ----
  u16* WembT = (u16*)alloc((size_t)512 * 128 * 2);
  u16* WqkvT = (u16*)alloc((size_t)6 * 1536 * 512 * 2);
  u16* WoutT = (u16*)alloc((size_t)6 * 512 * 512 * 2);
  u16* W1T   = (u16*)alloc((size_t)6 * 4096 * 512 * 2);
  u16* W2T   = (u16*)alloc((size_t)6 * 512 * 2048 * 2);
  u16* WdT   = (u16*)alloc((size_t)128 * 512 * 2);
  float* H   = (float*)alloc((size_t)NTOK * 512 * 4);
  u16* HB    = (u16*)alloc((size_t)NTOK * 512 * 2);
  float* DOTSP = (float*)alloc((size_t)8 * 32 * 4096 * 4);
  float* DOTS  = (float*)alloc((size_t)32 * 4096 * 4);
  // Union region U (64 MiB): XP@0 pre-loop; Y@0(16M) + QKV@16Mi(48M);
  // O@0 after Y dead; F@0(32M) after QKV/O dead.
  char* U = alloc((size_t)64 * 1024 * 1024);
  const size_t MI = 1024 * 1024;
  u16* XP  = (u16*)U;
  u16* Y   = (u16*)U;
  u16* QKV = (u16*)(U + 16 * MI);
  u16* O   = (u16*)U;
  u16* F   = (u16*)U;

  k_transpose<<<dim3(2, 8, 1),  256, 0, stream>>>(Wemb, WembT, 128, 512);
  k_transpose<<<dim3(8, 24, 6), 256, 0, stream>>>(Wqkv, WqkvT, 512, 1536);
  k_transpose<<<dim3(8, 8, 6),  256, 0, stream>>>(Wout, WoutT, 512, 512);
  k_transpose<<<dim3(8, 64, 6), 256, 0, stream>>>(W1, W1T, 512, 4096);
  k_transpose<<<dim3(32, 8, 6), 256, 0, stream>>>(W2, W2T, 2048, 512);
  k_transpose<<<dim3(8, 2, 1),  256, 0, stream>>>(Wd, WdT, 512, 128);

  k_packx<<<8192, 256, 0, stream>>>(x, XP);
  k_gemm<0><<<dim3(4, 128), 256, 0, stream>>>(XP, WembT, 128, bemb,
      nullptr, 1.f, H, nullptr, 0);

  for (int i = 0; i < 6; ++i) {
    k_ln<<<4096, 256, 0, stream>>>(H, lng + i * 512, lnb + i * 512, Y);
    k_gemmP<<<dim3(6, 64), 512, 0, stream>>>(Y, 512,
        WqkvT + (size_t)i * 1536 * 512, 512, QKV, 1536);
    k_dots<<<dim3(8, 32), 256, 0, stream>>>(QKV, DOTSP);
    k_reddots<<<512, 256, 0, stream>>>(DOTSP, DOTS);
    k_ov<<<dim3(64, 32), 256, 0, stream>>>(QKV, DOTS, O);
    k_gemm<2><<<dim3(4, 128), 256, 0, stream>>>(O,
        WoutT + (size_t)i * 512 * 512, 512, bout + i * 512, H, 1.f, H, HB, 512);
    k_gemmG<<<dim3(8, 128), 512, 0, stream>>>(HB, 512,
        W1T + (size_t)i * 4096 * 512,
        W1T + (size_t)i * 4096 * 512 + (size_t)2048 * 512, 512,
        b1 + i * 4096, F, 2048);
    k_gemm<2><<<dim3(4, 128), 256, 0, stream>>>(F,
        W2T + (size_t)i * 512 * 2048, 2048, b2 + i * 512, H, RSCL, H, HB, 512);
  }
  k_gemm<7><<<dim3(1, 128), 256, 0, stream>>>(HB, WdT, 512, bd,
      nullptr, 1.f, (float*)d_out, nullptr, 0);
}